// Round 7
// baseline (257.694 us; speedup 1.0000x reference)
//
#include <hip/hip_runtime.h>
#include <stdint.h>

// out[b, w, j] = sum_p x[b,j,p] * weight[j,p,w] + bias[j,w]
// x: [B,M,P] f32, weight: [M,P,W] f32, bias: [M,W] f32, out: [B,W,M] f32
// B=128, M=10000, P=64, W=24. HBM floor ~510-570 MB -> ~85 us.
//
// Round-7: x staged to LDS via global_load_lds with CONTIGUOUS 1KB/instr
// global reads (rounds 4-6's scattered per-lane rows never beat ~2.8 TB/s).
// Wave k owns j0+k, j0+8+k; lane = b; per-wave private 16KB slab, vmcnt(0)
// on own loads only -> zero barriers in compute, 8 independent pipelines.
// Weights via wave-uniform (scalar-path) loads -> no LDS broadcast tax.
// XOR-swizzled slab (pre-swizzled global src, linear LDS dest) makes the
// lane=b ds_read_b128 hit all 8 bank groups. obuf overlays slabs at the end.

constexpr int B  = 128;
constexpr int M  = 10000;
constexpr int P  = 64;
constexpr int W  = 24;

constexpr int JT  = 16;   // j per block
constexpr int BH  = 64;   // b per block
constexpr int NT  = 512;  // 8 waves; wave k does j0+k and j0+8+k
constexpr int NWG = (M / JT) * (B / BH);  // 1250

__global__ __launch_bounds__(NT, 2) void pcl_kernel(
    const float* __restrict__ x, const float* __restrict__ wgt,
    const float* __restrict__ bias, float* __restrict__ out) {
  // 8 slabs x 16KB = 128KB; obuf [24][16][18] (27.6KB) overlays after barrier
  __shared__ char smem[131072];
  float4* xs4  = reinterpret_cast<float4*>(smem);
  float*  obuf = reinterpret_cast<float*>(smem);

  const int t    = threadIdx.x;
  const int wk   = t >> 6;   // wave index = local j (per pass)
  const int lane = t & 63;   // lane = local b

  // bijective XCD swizzle (m204): 1250 = 8*156 + 2; (jt,by) pairs same XCD
  const int orig = blockIdx.x;
  const int xcd  = orig & 7;
  const int idx  = orig >> 3;
  const int wgid = (xcd < 2 ? xcd * 157 : 314 + (xcd - 2) * 156) + idx;
  const int jt = wgid >> 1;
  const int by = wgid & 1;
  const int j0 = jt * JT;
  const int b0 = by * BH;

  float acc[2][24];

#pragma unroll
  for (int pass = 0; pass < 2; ++pass) {
    const int jc = __builtin_amdgcn_readfirstlane(j0 + wk + 8 * pass);

    // WAR guard: slab rewrite (vmcnt-tracked LDS writes) vs pending ds_reads
    asm volatile("s_waitcnt lgkmcnt(0)" ::: "memory");

    // ---- stage this wave's slab: x[b0..b0+63][jc][0..63], 16KB ----
    // LDS slot s (f4): b = s>>4, c_slot = s&15 holds element c = c_slot^(b&15)
#pragma unroll
    for (int i = 0; i < 16; ++i) {
      const int sl = (i << 6) | lane;        // slot within slab
      const int bi = sl >> 4;                // local b of this slot
      const int c  = (sl & 15) ^ (bi & 15);  // swizzled f4 index
      const float* g = x + ((size_t)(b0 + bi) * M + jc) * P + 4 * c;
      char* d = smem + (wk << 14) + (i << 10);  // wave-uniform base
      __builtin_amdgcn_global_load_lds(
          (const __attribute__((address_space(1))) void*)g,
          (__attribute__((address_space(3))) void*)d, 16, 0, 0);
    }
    asm volatile("s_waitcnt vmcnt(0)" ::: "memory");
    __builtin_amdgcn_sched_barrier(0);

    // bias -> acc[pass] (wave-uniform loads)
    {
      const float4* bf = reinterpret_cast<const float4*>(bias + (size_t)jc * W);
#pragma unroll
      for (int q = 0; q < 6; ++q) {
        const float4 v = bf[q];
        acc[pass][4 * q + 0] = v.x;
        acc[pass][4 * q + 1] = v.y;
        acc[pass][4 * q + 2] = v.z;
        acc[pass][4 * q + 3] = v.w;
      }
    }

    // ---- compute: per chunk c: 1 ds_read_b128 (x) + 24 uniform w-f4 loads
    const float4* wf = reinterpret_cast<const float4*>(wgt + (size_t)jc * (P * W));
    const int xbase = (wk << 10) | (lane << 4);
#pragma unroll 2
    for (int c = 0; c < 16; ++c) {
      const float4 xv = xs4[xbase | (c ^ (lane & 15))];
#pragma unroll
      for (int pp = 0; pp < 4; ++pp) {
        const float xs = (pp == 0) ? xv.x : (pp == 1) ? xv.y
                        : (pp == 2) ? xv.z : xv.w;
        const float4* wp = wf + (size_t)(4 * c + pp) * 6;
        const float4 w0 = wp[0], w1 = wp[1], w2 = wp[2];
        const float4 w3 = wp[3], w4 = wp[4], w5 = wp[5];
        acc[pass][ 0] = fmaf(xs, w0.x, acc[pass][ 0]);
        acc[pass][ 1] = fmaf(xs, w0.y, acc[pass][ 1]);
        acc[pass][ 2] = fmaf(xs, w0.z, acc[pass][ 2]);
        acc[pass][ 3] = fmaf(xs, w0.w, acc[pass][ 3]);
        acc[pass][ 4] = fmaf(xs, w1.x, acc[pass][ 4]);
        acc[pass][ 5] = fmaf(xs, w1.y, acc[pass][ 5]);
        acc[pass][ 6] = fmaf(xs, w1.z, acc[pass][ 6]);
        acc[pass][ 7] = fmaf(xs, w1.w, acc[pass][ 7]);
        acc[pass][ 8] = fmaf(xs, w2.x, acc[pass][ 8]);
        acc[pass][ 9] = fmaf(xs, w2.y, acc[pass][ 9]);
        acc[pass][10] = fmaf(xs, w2.z, acc[pass][10]);
        acc[pass][11] = fmaf(xs, w2.w, acc[pass][11]);
        acc[pass][12] = fmaf(xs, w3.x, acc[pass][12]);
        acc[pass][13] = fmaf(xs, w3.y, acc[pass][13]);
        acc[pass][14] = fmaf(xs, w3.z, acc[pass][14]);
        acc[pass][15] = fmaf(xs, w3.w, acc[pass][15]);
        acc[pass][16] = fmaf(xs, w4.x, acc[pass][16]);
        acc[pass][17] = fmaf(xs, w4.y, acc[pass][17]);
        acc[pass][18] = fmaf(xs, w4.z, acc[pass][18]);
        acc[pass][19] = fmaf(xs, w4.w, acc[pass][19]);
        acc[pass][20] = fmaf(xs, w5.x, acc[pass][20]);
        acc[pass][21] = fmaf(xs, w5.y, acc[pass][21]);
        acc[pass][22] = fmaf(xs, w5.z, acc[pass][22]);
        acc[pass][23] = fmaf(xs, w5.w, acc[pass][23]);
      }
    }
  }

  // ---- stores: obuf overlays slabs; 4 b-rounds; 64B j-runs ----
  __syncthreads();  // all slab reads done before obuf overwrites
#pragma unroll
  for (int r = 0; r < 4; ++r) {
    if ((lane >> 4) == r) {
      const int b16 = lane & 15;
#pragma unroll
      for (int pass = 0; pass < 2; ++pass) {
        const int jl = wk + 8 * pass;
#pragma unroll
        for (int w = 0; w < W; ++w)
          obuf[(w * 16 + jl) * 18 + b16] = acc[pass][w];
      }
    }
    __syncthreads();  // obuf visible
#pragma unroll
    for (int it = 0; it < 3; ++it) {
      const int d   = t + it * NT;    // 0..1535
      const int jq  = d & 3;
      const int blr = (d >> 2) & 15;
      const int w   = d >> 6;         // 0..23
      float4 o;
      o.x = obuf[(w * 16 + 4 * jq + 0) * 18 + blr];
      o.y = obuf[(w * 16 + 4 * jq + 1) * 18 + blr];
      o.z = obuf[(w * 16 + 4 * jq + 2) * 18 + blr];
      o.w = obuf[(w * 16 + 4 * jq + 3) * 18 + blr];
      *reinterpret_cast<float4*>(
          out + ((size_t)(b0 + 16 * r + blr) * W + w) * M + j0 + 4 * jq) = o;
    }
    __syncthreads();  // drain reads done before next round's writes
  }
}

extern "C" void kernel_launch(void* const* d_in, const int* in_sizes, int n_in,
                              void* d_out, int out_size, void* d_ws, size_t ws_size,
                              hipStream_t stream) {
  const float* x    = (const float*)d_in[0];
  const float* wgt  = (const float*)d_in[1];
  const float* bias = (const float*)d_in[2];
  float* out        = (float*)d_out;

  dim3 grid(NWG);  // 1250
  dim3 block(NT);  // 512
  hipLaunchKernelGGL(pcl_kernel, grid, block, 0, stream, x, wgt, bias, out);
}